// Round 2
// baseline (492.028 us; speedup 1.0000x reference)
//
#include <hip/hip_runtime.h>
#include <stdint.h>

// Problem: Q[8192,512] f32, K[8192,512] f32 ->
//   scores_ij = -0.5*(sqrt(n2 + c*qd^2) + sqrt(n2 + c*kd^2)),
//   n2 = max(qq_i + kk_j - 2*qk_ij, 0), qd = qq_i - qk_ij, kd = qk_ij - kk_j
//   out = softmax(scores, axis=-1), f32 [8192,8192]
//
// Round-1 change: round-0 needed 24.1 MiB of d_ws; theory is ws_size is
// smaller and call 1 corrupted adjacent harness buffers (pristine input
// copies), making calls 2+ deterministically wrong. Now:
//   - fused per-row softmax (no pM/pS partials, no reduce/norm kernels)
//   - FAST path (ws >= 16.06 MiB): bf16 pre-copies + global_load_lds GEMM
//   - SAFE path (ws >= 64 KiB):    convert-during-staging GEMM, ws = qq/kk only

#define NQ 8192
#define NK 8192
#define DIM 512
#define CSCALE 0.01f

typedef float f32x4 __attribute__((ext_vector_type(4)));
typedef short s16x8 __attribute__((ext_vector_type(8)));

__device__ __forceinline__ unsigned short f2bf(float x) {
  // round-to-nearest-even f32 -> bf16 (inputs are finite normals)
  union { float f; uint32_t u; } c; c.f = x;
  uint32_t u = c.u;
  return (unsigned short)((u + 0x7fffu + ((u >> 16) & 1u)) >> 16);
}

__device__ __forceinline__ s16x8 pack8(f32x4 a, f32x4 b) {
  s16x8 r;
  r[0]=(short)f2bf(a.x); r[1]=(short)f2bf(a.y);
  r[2]=(short)f2bf(a.z); r[3]=(short)f2bf(a.w);
  r[4]=(short)f2bf(b.x); r[5]=(short)f2bf(b.y);
  r[6]=(short)f2bf(b.z); r[7]=(short)f2bf(b.w);
  return r;
}

// async global->LDS, 16B per lane; LDS dest is wave-uniform base + lane*16
#define GLOAD_LDS16(g, l)                                                      \
  __builtin_amdgcn_global_load_lds(                                            \
      (const __attribute__((address_space(1))) void*)(g),                      \
      (__attribute__((address_space(3))) void*)(l), 16, 0, 0)

// ------------------------------------------------------------- prep (FAST)
__global__ __launch_bounds__(256) void prep_full_kernel(
    const float* __restrict__ q, const float* __restrict__ k,
    unsigned short* __restrict__ qbf, unsigned short* __restrict__ kbf,
    float* __restrict__ qq, float* __restrict__ kk) {
  int rowg = blockIdx.x * 4 + (threadIdx.x >> 6);  // 0..16383
  int lane = threadIdx.x & 63;
  const float* src; unsigned short* dst; float* nrm; int row;
  if (rowg < NQ) { src = q; dst = qbf; nrm = qq; row = rowg; }
  else           { src = k; dst = kbf; nrm = kk; row = rowg - NQ; }
  const float* p = src + (size_t)row * DIM + lane * 8;
  f32x4 a = *(const f32x4*)p;
  f32x4 b = *(const f32x4*)(p + 4);
  float ss = a.x*a.x + a.y*a.y + a.z*a.z + a.w*a.w
           + b.x*b.x + b.y*b.y + b.z*b.z + b.w*b.w;
  *(s16x8*)(dst + (size_t)row * DIM + lane * 8) = pack8(a, b);
#pragma unroll
  for (int mask = 1; mask < 64; mask <<= 1) ss += __shfl_xor(ss, mask, 64);
  if (lane == 0) nrm[row] = ss;
}

// ------------------------------------------------------------- prep (SAFE)
__global__ __launch_bounds__(256) void prep_norms_kernel(
    const float* __restrict__ q, const float* __restrict__ k,
    float* __restrict__ qq, float* __restrict__ kk) {
  int rowg = blockIdx.x * 4 + (threadIdx.x >> 6);
  int lane = threadIdx.x & 63;
  const float* src; float* nrm; int row;
  if (rowg < NQ) { src = q; nrm = qq; row = rowg; }
  else           { src = k; nrm = kk; row = rowg - NQ; }
  const float* p = src + (size_t)row * DIM + lane * 8;
  f32x4 a = *(const f32x4*)p;
  f32x4 b = *(const f32x4*)(p + 4);
  float ss = a.x*a.x + a.y*a.y + a.z*a.z + a.w*a.w
           + b.x*b.x + b.y*b.y + b.z*b.z + b.w*b.w;
#pragma unroll
  for (int mask = 1; mask < 64; mask <<= 1) ss += __shfl_xor(ss, mask, 64);
  if (lane == 0) nrm[row] = ss;
}

// ---- shared epilogue: scores from acc -> S ------------------------------
// C/D layout of mfma_f32_16x16x32_bf16: col = lane&15, row = quad*4 + reg
__device__ __forceinline__ void score_epilogue(
    const f32x4 acc[4][4], const float* __restrict__ qq,
    const float* __restrict__ kk, float* __restrict__ S,
    int m0, int n0, int wr, int wc, int quad, int lcol) {
  float kkv[4];
#pragma unroll
  for (int ni = 0; ni < 4; ++ni) kkv[ni] = kk[n0 + wc * 64 + ni * 16 + lcol];
#pragma unroll
  for (int mi = 0; mi < 4; ++mi) {
    const int ibase = m0 + wr * 64 + mi * 16 + quad * 4;  // rows ibase..+3
    float qqv[4];
#pragma unroll
    for (int r = 0; r < 4; ++r) qqv[r] = qq[ibase + r];
#pragma unroll
    for (int ni = 0; ni < 4; ++ni) {
      const int col = n0 + wc * 64 + ni * 16 + lcol;
#pragma unroll
      for (int r = 0; r < 4; ++r) {
        float qkv = acc[mi][ni][r];
        float n2 = fmaxf(qqv[r] + kkv[ni] - 2.f * qkv, 0.f);
        float qd = qqv[r] - qkv;
        float kd = qkv - kkv[ni];
        float s = -0.5f * (sqrtf(n2 + CSCALE * qd * qd) +
                           sqrtf(n2 + CSCALE * kd * kd));
        S[(size_t)(ibase + r) * NK + col] = s;
      }
    }
  }
}

// ------------------------------------------------------------- GEMM (FAST)
// 128x128 tile, 256 threads = 4 waves (2x2 of 64x64), BK=32, 16x16x32 MFMA.
__global__ __launch_bounds__(256) void gemm_fast_kernel(
    const unsigned short* __restrict__ qbf, const unsigned short* __restrict__ kbf,
    const float* __restrict__ qq, const float* __restrict__ kk,
    float* __restrict__ S) {
  __shared__ unsigned short lA[128 * 32];  // 8 KB, row-major [row][k]
  __shared__ unsigned short lB[128 * 32];
  const int tid = threadIdx.x;
  const int m0 = blockIdx.y * 128;
  const int n0 = blockIdx.x * 128;
  const int wave = tid >> 6, lane = tid & 63;
  const int wr = wave >> 1, wc = wave & 1;
  const int quad = lane >> 4, lcol = lane & 15;

  const unsigned short* ga = qbf + (size_t)(m0 + (tid >> 2)) * DIM + (tid & 3) * 8;
  const unsigned short* gb = kbf + (size_t)(n0 + (tid >> 2)) * DIM + (tid & 3) * 8;
  char* la0 = (char*)lA + wave * 1024;  // wave-uniform LDS base
  char* lb0 = (char*)lB + wave * 1024;

  f32x4 acc[4][4];
#pragma unroll
  for (int mi = 0; mi < 4; ++mi)
#pragma unroll
    for (int ni = 0; ni < 4; ++ni) acc[mi][ni] = f32x4{0.f, 0.f, 0.f, 0.f};

  const s16x8* lA8 = (const s16x8*)lA;
  const s16x8* lB8 = (const s16x8*)lB;
  const int arow = wr * 64 + lcol;  // A frag: m = lane&15, k = quad*8+j
  const int brow = wc * 64 + lcol;

  for (int kt = 0; kt < DIM / 32; ++kt) {
    const int ko = kt * 32;
    GLOAD_LDS16(ga + ko, la0);
    GLOAD_LDS16(ga + ko + 64 * DIM, la0 + 4096);
    GLOAD_LDS16(gb + ko, lb0);
    GLOAD_LDS16(gb + ko + 64 * DIM, lb0 + 4096);
    __syncthreads();
    s16x8 af[4], bfr[4];
#pragma unroll
    for (int mi = 0; mi < 4; ++mi) af[mi] = lA8[(arow + mi * 16) * 4 + quad];
#pragma unroll
    for (int ni = 0; ni < 4; ++ni) bfr[ni] = lB8[(brow + ni * 16) * 4 + quad];
#pragma unroll
    for (int mi = 0; mi < 4; ++mi)
#pragma unroll
      for (int ni = 0; ni < 4; ++ni)
        acc[mi][ni] = __builtin_amdgcn_mfma_f32_16x16x32_bf16(
            af[mi], bfr[ni], acc[mi][ni], 0, 0, 0);
    __syncthreads();
  }
  score_epilogue(acc, qq, kk, S, m0, n0, wr, wc, quad, lcol);
}

// ------------------------------------------------------------- GEMM (SAFE)
// Same MFMA core; staging loads f32 from q/k, converts to bf16, ds_writes.
__global__ __launch_bounds__(256) void gemm_safe_kernel(
    const float* __restrict__ q, const float* __restrict__ k,
    const float* __restrict__ qq, const float* __restrict__ kk,
    float* __restrict__ S) {
  __shared__ unsigned short lA[128 * 32];
  __shared__ unsigned short lB[128 * 32];
  const int tid = threadIdx.x;
  const int m0 = blockIdx.y * 128;
  const int n0 = blockIdx.x * 128;
  const int wave = tid >> 6, lane = tid & 63;
  const int wr = wave >> 1, wc = wave & 1;
  const int quad = lane >> 4, lcol = lane & 15;

  // staging: thread t owns row t/2, k-half (t&1)*16 of the 128x32 tile
  const float* gaf = q + (size_t)(m0 + (tid >> 1)) * DIM + (tid & 1) * 16;
  const float* gbf = k + (size_t)(n0 + (tid >> 1)) * DIM + (tid & 1) * 16;
  unsigned short* wA = lA + (tid >> 1) * 32 + (tid & 1) * 16;
  unsigned short* wB = lB + (tid >> 1) * 32 + (tid & 1) * 16;

  f32x4 acc[4][4];
#pragma unroll
  for (int mi = 0; mi < 4; ++mi)
#pragma unroll
    for (int ni = 0; ni < 4; ++ni) acc[mi][ni] = f32x4{0.f, 0.f, 0.f, 0.f};

  const s16x8* lA8 = (const s16x8*)lA;
  const s16x8* lB8 = (const s16x8*)lB;
  const int arow = wr * 64 + lcol;
  const int brow = wc * 64 + lcol;

  for (int kt = 0; kt < DIM / 32; ++kt) {
    const float* pa = gaf + kt * 32;
    const float* pb = gbf + kt * 32;
    f32x4 a0 = *(const f32x4*)(pa), a1 = *(const f32x4*)(pa + 4);
    f32x4 a2 = *(const f32x4*)(pa + 8), a3 = *(const f32x4*)(pa + 12);
    f32x4 b0 = *(const f32x4*)(pb), b1 = *(const f32x4*)(pb + 4);
    f32x4 b2 = *(const f32x4*)(pb + 8), b3 = *(const f32x4*)(pb + 12);
    *(s16x8*)wA = pack8(a0, a1);
    *(s16x8*)(wA + 8) = pack8(a2, a3);
    *(s16x8*)wB = pack8(b0, b1);
    *(s16x8*)(wB + 8) = pack8(b2, b3);
    __syncthreads();
    s16x8 af[4], bfr[4];
#pragma unroll
    for (int mi = 0; mi < 4; ++mi) af[mi] = lA8[(arow + mi * 16) * 4 + quad];
#pragma unroll
    for (int ni = 0; ni < 4; ++ni) bfr[ni] = lB8[(brow + ni * 16) * 4 + quad];
#pragma unroll
    for (int mi = 0; mi < 4; ++mi)
#pragma unroll
      for (int ni = 0; ni < 4; ++ni)
        acc[mi][ni] = __builtin_amdgcn_mfma_f32_16x16x32_bf16(
            af[mi], bfr[ni], acc[mi][ni], 0, 0, 0);
    __syncthreads();
  }
  score_epilogue(acc, qq, kk, S, m0, n0, wr, wc, quad, lcol);
}

// --------------------------------------------------------- fused row softmax
// One block per row; row data held in registers (32 f32/thread), in-place.
__global__ __launch_bounds__(256) void rowsoftmax_kernel(float* __restrict__ S) {
  __shared__ float red[8];
  const int t = threadIdx.x;
  const int wave = t >> 6, lane = t & 63;
  float* Srow = S + (size_t)blockIdx.x * NK;
  f32x4 v[8];
  float m = -1e30f;
#pragma unroll
  for (int j = 0; j < 8; ++j) {
    v[j] = *(const f32x4*)(Srow + j * 1024 + t * 4);
    m = fmaxf(m, fmaxf(fmaxf(v[j].x, v[j].y), fmaxf(v[j].z, v[j].w)));
  }
#pragma unroll
  for (int mask = 1; mask < 64; mask <<= 1) m = fmaxf(m, __shfl_xor(m, mask, 64));
  if (lane == 0) red[wave] = m;
  __syncthreads();
  m = fmaxf(fmaxf(red[0], red[1]), fmaxf(red[2], red[3]));
  float s = 0.f;
#pragma unroll
  for (int j = 0; j < 8; ++j) {
    v[j].x = __expf(v[j].x - m);
    v[j].y = __expf(v[j].y - m);
    v[j].z = __expf(v[j].z - m);
    v[j].w = __expf(v[j].w - m);
    s += (v[j].x + v[j].y) + (v[j].z + v[j].w);
  }
#pragma unroll
  for (int mask = 1; mask < 64; mask <<= 1) s += __shfl_xor(s, mask, 64);
  if (lane == 0) red[4 + wave] = s;
  __syncthreads();
  float z = 1.0f / ((red[4] + red[5]) + (red[6] + red[7]));
#pragma unroll
  for (int j = 0; j < 8; ++j) {
    v[j].x *= z; v[j].y *= z; v[j].z *= z; v[j].w *= z;
    *(f32x4*)(Srow + j * 1024 + t * 4) = v[j];
  }
}

// ---------------------------------------------------------------- launch
extern "C" void kernel_launch(void* const* d_in, const int* in_sizes, int n_in,
                              void* d_out, int out_size, void* d_ws, size_t ws_size,
                              hipStream_t stream) {
  const float* q = (const float*)d_in[0];
  const float* k = (const float*)d_in[1];
  float* S = (float*)d_out;
  char* ws = (char*)d_ws;

  // FAST needs qbf(8M) + kbf(8M) + qq(32K) + kk(32K) = 16,842,752 bytes.
  const bool fast = ws_size >= (size_t)16842752;
  if (fast) {
    unsigned short* qbf = (unsigned short*)(ws);
    unsigned short* kbf = (unsigned short*)(ws + 8388608);
    float* qq = (float*)(ws + 16777216);
    float* kk = (float*)(ws + 16777216 + 32768);
    prep_full_kernel<<<4096, 256, 0, stream>>>(q, k, qbf, kbf, qq, kk);
    gemm_fast_kernel<<<dim3(64, 64), 256, 0, stream>>>(qbf, kbf, qq, kk, S);
  } else {
    float* qq = (float*)(ws);
    float* kk = (float*)(ws + 32768);
    prep_norms_kernel<<<4096, 256, 0, stream>>>(q, k, qq, kk);
    gemm_safe_kernel<<<dim3(64, 64), 256, 0, stream>>>(q, k, qq, kk, S);
  }
  rowsoftmax_kernel<<<NQ, 256, 0, stream>>>(S);
}

// Round 3
// 466.847 us; speedup vs baseline: 1.0539x; 1.0539x over previous
//
#include <hip/hip_runtime.h>
#include <stdint.h>

// Problem: Q[8192,512] f32, K[8192,512] f32 ->
//   scores_ij = -0.5*(sqrt(n2 + c*qd^2) + sqrt(n2 + c*kd^2)),
//   n2 = max(qq_i + kk_j - 2*qk_ij, 0), qd = qq_i - qk_ij, kd = qk_ij - kk_j
//   out = softmax(scores, axis=-1), f32 [8192,8192]
//
// Round-3: scores <= 0 and bounded => exp(s) needs no max subtraction.
// FAST path stores E = exp(s) as bf16 (128 MB intermediate instead of 256 MB
// f32), via LDS-transposed fully-coalesced 128B-line stores; final pass
// row-sums E and writes E/Z. Round-2's verified kernels kept as fallbacks.

#define NQ 8192
#define NK 8192
#define DIM 512
#define CSCALE 0.01f

typedef float f32x4 __attribute__((ext_vector_type(4)));
typedef short s16x8 __attribute__((ext_vector_type(8)));
typedef unsigned short u16x4 __attribute__((ext_vector_type(4)));

__device__ __forceinline__ unsigned short f2bf(float x) {
  // round-to-nearest-even f32 -> bf16 (finite, non-negative here)
  union { float f; uint32_t u; } c; c.f = x;
  uint32_t u = c.u;
  return (unsigned short)((u + 0x7fffu + ((u >> 16) & 1u)) >> 16);
}

__device__ __forceinline__ float bf2f(unsigned short h) {
  union { uint32_t u; float f; } c; c.u = ((uint32_t)h) << 16;
  return c.f;
}

__device__ __forceinline__ s16x8 pack8(f32x4 a, f32x4 b) {
  s16x8 r;
  r[0]=(short)f2bf(a.x); r[1]=(short)f2bf(a.y);
  r[2]=(short)f2bf(a.z); r[3]=(short)f2bf(a.w);
  r[4]=(short)f2bf(b.x); r[5]=(short)f2bf(b.y);
  r[6]=(short)f2bf(b.z); r[7]=(short)f2bf(b.w);
  return r;
}

// async global->LDS, 16B per lane; LDS dest is wave-uniform base + lane*16
#define GLOAD_LDS16(g, l)                                                      \
  __builtin_amdgcn_global_load_lds(                                            \
      (const __attribute__((address_space(1))) void*)(g),                      \
      (__attribute__((address_space(3))) void*)(l), 16, 0, 0)

// ------------------------------------------------------------- prep (FAST)
__global__ __launch_bounds__(256) void prep_full_kernel(
    const float* __restrict__ q, const float* __restrict__ k,
    unsigned short* __restrict__ qbf, unsigned short* __restrict__ kbf,
    float* __restrict__ qq, float* __restrict__ kk) {
  int rowg = blockIdx.x * 4 + (threadIdx.x >> 6);  // 0..16383
  int lane = threadIdx.x & 63;
  const float* src; unsigned short* dst; float* nrm; int row;
  if (rowg < NQ) { src = q; dst = qbf; nrm = qq; row = rowg; }
  else           { src = k; dst = kbf; nrm = kk; row = rowg - NQ; }
  const float* p = src + (size_t)row * DIM + lane * 8;
  f32x4 a = *(const f32x4*)p;
  f32x4 b = *(const f32x4*)(p + 4);
  float ss = a.x*a.x + a.y*a.y + a.z*a.z + a.w*a.w
           + b.x*b.x + b.y*b.y + b.z*b.z + b.w*b.w;
  *(s16x8*)(dst + (size_t)row * DIM + lane * 8) = pack8(a, b);
#pragma unroll
  for (int mask = 1; mask < 64; mask <<= 1) ss += __shfl_xor(ss, mask, 64);
  if (lane == 0) nrm[row] = ss;
}

// ------------------------------------------------------------- prep (SAFE)
__global__ __launch_bounds__(256) void prep_norms_kernel(
    const float* __restrict__ q, const float* __restrict__ k,
    float* __restrict__ qq, float* __restrict__ kk) {
  int rowg = blockIdx.x * 4 + (threadIdx.x >> 6);
  int lane = threadIdx.x & 63;
  const float* src; float* nrm; int row;
  if (rowg < NQ) { src = q; nrm = qq; row = rowg; }
  else           { src = k; nrm = kk; row = rowg - NQ; }
  const float* p = src + (size_t)row * DIM + lane * 8;
  f32x4 a = *(const f32x4*)p;
  f32x4 b = *(const f32x4*)(p + 4);
  float ss = a.x*a.x + a.y*a.y + a.z*a.z + a.w*a.w
           + b.x*b.x + b.y*b.y + b.z*b.z + b.w*b.w;
#pragma unroll
  for (int mask = 1; mask < 64; mask <<= 1) ss += __shfl_xor(ss, mask, 64);
  if (lane == 0) nrm[row] = ss;
}

// ---- score from qk accumulator --------------------------------------------
__device__ __forceinline__ float score_fn(float qkv, float qqv, float kkv) {
  float n2 = fmaxf(qqv + kkv - 2.f * qkv, 0.f);
  float qd = qqv - qkv;
  float kd = qkv - kkv;
  return -0.5f * (sqrtf(n2 + CSCALE * qd * qd) +
                  sqrtf(n2 + CSCALE * kd * kd));
}

// ------------------------------------------------------------- GEMM (FAST)
// 128x128 tile, 256 threads = 4 waves (2x2 of 64x64), BK=32, 16x16x32 MFMA.
// Epilogue: E = exp(score) -> bf16, per-wave LDS transpose (XOR col-group
// swizzle, conflict-free b16 writes / aligned b128 reads), 128B-line stores.
__global__ __launch_bounds__(256) void gemm_exp_kernel(
    const unsigned short* __restrict__ qbf, const unsigned short* __restrict__ kbf,
    const float* __restrict__ qq, const float* __restrict__ kk,
    unsigned short* __restrict__ E) {
  __shared__ unsigned short lA[128 * 32];            // 8 KB, row-major [row][k]
  __shared__ unsigned short lB[128 * 32];            // 8 KB
  __shared__ alignas(16) unsigned short lT[4][16 * 80];  // 10 KB transpose pads
  const int tid = threadIdx.x;
  const int m0 = blockIdx.y * 128;
  const int n0 = blockIdx.x * 128;
  const int wave = tid >> 6, lane = tid & 63;
  const int wr = wave >> 1, wc = wave & 1;
  const int quad = lane >> 4, lcol = lane & 15;

  const unsigned short* ga = qbf + (size_t)(m0 + (tid >> 2)) * DIM + (tid & 3) * 8;
  const unsigned short* gb = kbf + (size_t)(n0 + (tid >> 2)) * DIM + (tid & 3) * 8;
  char* la0 = (char*)lA + wave * 1024;  // wave-uniform LDS base
  char* lb0 = (char*)lB + wave * 1024;

  f32x4 acc[4][4];
#pragma unroll
  for (int mi = 0; mi < 4; ++mi)
#pragma unroll
    for (int ni = 0; ni < 4; ++ni) acc[mi][ni] = f32x4{0.f, 0.f, 0.f, 0.f};

  const s16x8* lA8 = (const s16x8*)lA;
  const s16x8* lB8 = (const s16x8*)lB;
  const int arow = wr * 64 + lcol;  // A frag: m = lane&15, k = quad*8+j
  const int brow = wc * 64 + lcol;

  for (int kt = 0; kt < DIM / 32; ++kt) {
    const int ko = kt * 32;
    GLOAD_LDS16(ga + ko, la0);
    GLOAD_LDS16(ga + ko + 64 * DIM, la0 + 4096);
    GLOAD_LDS16(gb + ko, lb0);
    GLOAD_LDS16(gb + ko + 64 * DIM, lb0 + 4096);
    __syncthreads();
    s16x8 af[4], bfr[4];
#pragma unroll
    for (int mi = 0; mi < 4; ++mi) af[mi] = lA8[(arow + mi * 16) * 4 + quad];
#pragma unroll
    for (int ni = 0; ni < 4; ++ni) bfr[ni] = lB8[(brow + ni * 16) * 4 + quad];
#pragma unroll
    for (int mi = 0; mi < 4; ++mi)
#pragma unroll
      for (int ni = 0; ni < 4; ++ni)
        acc[mi][ni] = __builtin_amdgcn_mfma_f32_16x16x32_bf16(
            af[mi], bfr[ni], acc[mi][ni], 0, 0, 0);
    __syncthreads();
  }

  // ---- epilogue ----
  // C/D layout: col = lane&15, row = quad*4 + reg  [verified m89/m91 + R2 pass]
  unsigned short* tw = &lT[wave][0];  // wave-private 16x80 shorts
  float kkv[4];
#pragma unroll
  for (int ni = 0; ni < 4; ++ni) kkv[ni] = kk[n0 + wc * 64 + ni * 16 + lcol];
#pragma unroll
  for (int mi = 0; mi < 4; ++mi) {
    const int ibase = m0 + wr * 64 + mi * 16 + quad * 4;  // rows ibase..+3
    float qqv[4];
#pragma unroll
    for (int r = 0; r < 4; ++r) qqv[r] = qq[ibase + r];
    // write: row16 = quad*4+r, stored col-group = ni ^ quad (bank spread)
#pragma unroll
    for (int ni = 0; ni < 4; ++ni)
#pragma unroll
      for (int r = 0; r < 4; ++r) {
        float e = __expf(score_fn(acc[mi][ni][r], qqv[r], kkv[ni]));
        tw[(quad * 4 + r) * 80 + ((ni ^ quad) * 16 + lcol)] = f2bf(e);
      }
    // read 16B/lane, 8 lanes cover one row's 64 cols = 128B line
#pragma unroll
    for (int j = 0; j < 2; ++j) {
      const int row16 = (lane >> 3) + j * 8;
      const int g = (lane & 7) >> 1;            // global col group 0..3
      const int off = row16 * 80 + ((g ^ (row16 >> 2)) * 16) + (lane & 1) * 8;
      s16x8 vv = *(const s16x8*)(tw + off);
      const int rowg = m0 + wr * 64 + mi * 16 + row16;
      *(s16x8*)(E + (size_t)rowg * NK + n0 + wc * 64 + (lane & 7) * 8) = vv;
    }
  }
}

// ------------------------------------------------- row sum + scale (FAST)
// One block per row: read bf16 E (16 KB), Z = sum (f32), write E/Z as f32.
__global__ __launch_bounds__(256) void rowsum_scale_kernel(
    const unsigned short* __restrict__ E, float* __restrict__ out) {
  __shared__ float red[4];
  const int t = threadIdx.x;
  const int wave = t >> 6, lane = t & 63;
  const unsigned short* Erow = E + (size_t)blockIdx.x * NK;
  float* Orow = out + (size_t)blockIdx.x * NK;
  u16x4 ev[8];
  float s = 0.f;
#pragma unroll
  for (int j = 0; j < 8; ++j) {
    ev[j] = *(const u16x4*)(Erow + j * 1024 + t * 4);
    s += (bf2f(ev[j][0]) + bf2f(ev[j][1])) + (bf2f(ev[j][2]) + bf2f(ev[j][3]));
  }
#pragma unroll
  for (int mask = 1; mask < 64; mask <<= 1) s += __shfl_xor(s, mask, 64);
  if (lane == 0) red[wave] = s;
  __syncthreads();
  float z = 1.0f / ((red[0] + red[1]) + (red[2] + red[3]));
#pragma unroll
  for (int j = 0; j < 8; ++j) {
    f32x4 v;
    v.x = bf2f(ev[j][0]) * z;
    v.y = bf2f(ev[j][1]) * z;
    v.z = bf2f(ev[j][2]) * z;
    v.w = bf2f(ev[j][3]) * z;
    *(f32x4*)(Orow + j * 1024 + t * 4) = v;
  }
}

// ================== round-2 verified fallback kernels (MID / SAFE) ==========
__device__ __forceinline__ void score_epilogue(
    const f32x4 acc[4][4], const float* __restrict__ qq,
    const float* __restrict__ kk, float* __restrict__ S,
    int m0, int n0, int wr, int wc, int quad, int lcol) {
  float kkv[4];
#pragma unroll
  for (int ni = 0; ni < 4; ++ni) kkv[ni] = kk[n0 + wc * 64 + ni * 16 + lcol];
#pragma unroll
  for (int mi = 0; mi < 4; ++mi) {
    const int ibase = m0 + wr * 64 + mi * 16 + quad * 4;
    float qqv[4];
#pragma unroll
    for (int r = 0; r < 4; ++r) qqv[r] = qq[ibase + r];
#pragma unroll
    for (int ni = 0; ni < 4; ++ni) {
      const int col = n0 + wc * 64 + ni * 16 + lcol;
#pragma unroll
      for (int r = 0; r < 4; ++r)
        S[(size_t)(ibase + r) * NK + col] = score_fn(acc[mi][ni][r], qqv[r], kkv[ni]);
    }
  }
}

__global__ __launch_bounds__(256) void gemm_fast_kernel(
    const unsigned short* __restrict__ qbf, const unsigned short* __restrict__ kbf,
    const float* __restrict__ qq, const float* __restrict__ kk,
    float* __restrict__ S) {
  __shared__ unsigned short lA[128 * 32];
  __shared__ unsigned short lB[128 * 32];
  const int tid = threadIdx.x;
  const int m0 = blockIdx.y * 128;
  const int n0 = blockIdx.x * 128;
  const int wave = tid >> 6, lane = tid & 63;
  const int wr = wave >> 1, wc = wave & 1;
  const int quad = lane >> 4, lcol = lane & 15;
  const unsigned short* ga = qbf + (size_t)(m0 + (tid >> 2)) * DIM + (tid & 3) * 8;
  const unsigned short* gb = kbf + (size_t)(n0 + (tid >> 2)) * DIM + (tid & 3) * 8;
  char* la0 = (char*)lA + wave * 1024;
  char* lb0 = (char*)lB + wave * 1024;
  f32x4 acc[4][4];
#pragma unroll
  for (int mi = 0; mi < 4; ++mi)
#pragma unroll
    for (int ni = 0; ni < 4; ++ni) acc[mi][ni] = f32x4{0.f, 0.f, 0.f, 0.f};
  const s16x8* lA8 = (const s16x8*)lA;
  const s16x8* lB8 = (const s16x8*)lB;
  const int arow = wr * 64 + lcol;
  const int brow = wc * 64 + lcol;
  for (int kt = 0; kt < DIM / 32; ++kt) {
    const int ko = kt * 32;
    GLOAD_LDS16(ga + ko, la0);
    GLOAD_LDS16(ga + ko + 64 * DIM, la0 + 4096);
    GLOAD_LDS16(gb + ko, lb0);
    GLOAD_LDS16(gb + ko + 64 * DIM, lb0 + 4096);
    __syncthreads();
    s16x8 af[4], bfr[4];
#pragma unroll
    for (int mi = 0; mi < 4; ++mi) af[mi] = lA8[(arow + mi * 16) * 4 + quad];
#pragma unroll
    for (int ni = 0; ni < 4; ++ni) bfr[ni] = lB8[(brow + ni * 16) * 4 + quad];
#pragma unroll
    for (int mi = 0; mi < 4; ++mi)
#pragma unroll
      for (int ni = 0; ni < 4; ++ni)
        acc[mi][ni] = __builtin_amdgcn_mfma_f32_16x16x32_bf16(
            af[mi], bfr[ni], acc[mi][ni], 0, 0, 0);
    __syncthreads();
  }
  score_epilogue(acc, qq, kk, S, m0, n0, wr, wc, quad, lcol);
}

__global__ __launch_bounds__(256) void gemm_safe_kernel(
    const float* __restrict__ q, const float* __restrict__ k,
    const float* __restrict__ qq, const float* __restrict__ kk,
    float* __restrict__ S) {
  __shared__ unsigned short lA[128 * 32];
  __shared__ unsigned short lB[128 * 32];
  const int tid = threadIdx.x;
  const int m0 = blockIdx.y * 128;
  const int n0 = blockIdx.x * 128;
  const int wave = tid >> 6, lane = tid & 63;
  const int wr = wave >> 1, wc = wave & 1;
  const int quad = lane >> 4, lcol = lane & 15;
  const float* gaf = q + (size_t)(m0 + (tid >> 1)) * DIM + (tid & 1) * 16;
  const float* gbf = k + (size_t)(n0 + (tid >> 1)) * DIM + (tid & 1) * 16;
  unsigned short* wA = lA + (tid >> 1) * 32 + (tid & 1) * 16;
  unsigned short* wB = lB + (tid >> 1) * 32 + (tid & 1) * 16;
  f32x4 acc[4][4];
#pragma unroll
  for (int mi = 0; mi < 4; ++mi)
#pragma unroll
    for (int ni = 0; ni < 4; ++ni) acc[mi][ni] = f32x4{0.f, 0.f, 0.f, 0.f};
  const s16x8* lA8 = (const s16x8*)lA;
  const s16x8* lB8 = (const s16x8*)lB;
  const int arow = wr * 64 + lcol;
  const int brow = wc * 64 + lcol;
  for (int kt = 0; kt < DIM / 32; ++kt) {
    const float* pa = gaf + kt * 32;
    const float* pb = gbf + kt * 32;
    f32x4 a0 = *(const f32x4*)(pa), a1 = *(const f32x4*)(pa + 4);
    f32x4 a2 = *(const f32x4*)(pa + 8), a3 = *(const f32x4*)(pa + 12);
    f32x4 b0 = *(const f32x4*)(pb), b1 = *(const f32x4*)(pb + 4);
    f32x4 b2 = *(const f32x4*)(pb + 8), b3 = *(const f32x4*)(pb + 12);
    *(s16x8*)wA = pack8(a0, a1);
    *(s16x8*)(wA + 8) = pack8(a2, a3);
    *(s16x8*)wB = pack8(b0, b1);
    *(s16x8*)(wB + 8) = pack8(b2, b3);
    __syncthreads();
    s16x8 af[4], bfr[4];
#pragma unroll
    for (int mi = 0; mi < 4; ++mi) af[mi] = lA8[(arow + mi * 16) * 4 + quad];
#pragma unroll
    for (int ni = 0; ni < 4; ++ni) bfr[ni] = lB8[(brow + ni * 16) * 4 + quad];
#pragma unroll
    for (int mi = 0; mi < 4; ++mi)
#pragma unroll
      for (int ni = 0; ni < 4; ++ni)
        acc[mi][ni] = __builtin_amdgcn_mfma_f32_16x16x32_bf16(
            af[mi], bfr[ni], acc[mi][ni], 0, 0, 0);
    __syncthreads();
  }
  score_epilogue(acc, qq, kk, S, m0, n0, wr, wc, quad, lcol);
}

__global__ __launch_bounds__(256) void rowsoftmax_kernel(float* __restrict__ S) {
  __shared__ float red[8];
  const int t = threadIdx.x;
  const int wave = t >> 6, lane = t & 63;
  float* Srow = S + (size_t)blockIdx.x * NK;
  f32x4 v[8];
  float m = -1e30f;
#pragma unroll
  for (int j = 0; j < 8; ++j) {
    v[j] = *(const f32x4*)(Srow + j * 1024 + t * 4);
    m = fmaxf(m, fmaxf(fmaxf(v[j].x, v[j].y), fmaxf(v[j].z, v[j].w)));
  }
#pragma unroll
  for (int mask = 1; mask < 64; mask <<= 1) m = fmaxf(m, __shfl_xor(m, mask, 64));
  if (lane == 0) red[wave] = m;
  __syncthreads();
  m = fmaxf(fmaxf(red[0], red[1]), fmaxf(red[2], red[3]));
  float s = 0.f;
#pragma unroll
  for (int j = 0; j < 8; ++j) {
    v[j].x = __expf(v[j].x - m);
    v[j].y = __expf(v[j].y - m);
    v[j].z = __expf(v[j].z - m);
    v[j].w = __expf(v[j].w - m);
    s += (v[j].x + v[j].y) + (v[j].z + v[j].w);
  }
#pragma unroll
  for (int mask = 1; mask < 64; mask <<= 1) s += __shfl_xor(s, mask, 64);
  if (lane == 0) red[4 + wave] = s;
  __syncthreads();
  float z = 1.0f / ((red[4] + red[5]) + (red[6] + red[7]));
#pragma unroll
  for (int j = 0; j < 8; ++j) {
    v[j].x *= z; v[j].y *= z; v[j].z *= z; v[j].w *= z;
    *(f32x4*)(Srow + j * 1024 + t * 4) = v[j];
  }
}

// ---------------------------------------------------------------- launch
extern "C" void kernel_launch(void* const* d_in, const int* in_sizes, int n_in,
                              void* d_out, int out_size, void* d_ws, size_t ws_size,
                              hipStream_t stream) {
  const float* q = (const float*)d_in[0];
  const float* k = (const float*)d_in[1];
  float* S = (float*)d_out;
  char* ws = (char*)d_ws;

  // FAST: qbf(8M) + kbf(8M) + qq(32K) + kk(32K) + E(128M) = 151,126,016 B
  if (ws_size >= (size_t)151126016) {
    unsigned short* qbf = (unsigned short*)(ws);
    unsigned short* kbf = (unsigned short*)(ws + 8388608);
    float* qq = (float*)(ws + 16777216);
    float* kk = (float*)(ws + 16777216 + 32768);
    unsigned short* E = (unsigned short*)(ws + 16908288);
    prep_full_kernel<<<4096, 256, 0, stream>>>(q, k, qbf, kbf, qq, kk);
    gemm_exp_kernel<<<dim3(64, 64), 256, 0, stream>>>(qbf, kbf, qq, kk, E);
    rowsum_scale_kernel<<<NQ, 256, 0, stream>>>(E, S);
  } else if (ws_size >= (size_t)16842752) {  // MID: round-2 verified path
    unsigned short* qbf = (unsigned short*)(ws);
    unsigned short* kbf = (unsigned short*)(ws + 8388608);
    float* qq = (float*)(ws + 16777216);
    float* kk = (float*)(ws + 16777216 + 32768);
    prep_full_kernel<<<4096, 256, 0, stream>>>(q, k, qbf, kbf, qq, kk);
    gemm_fast_kernel<<<dim3(64, 64), 256, 0, stream>>>(qbf, kbf, qq, kk, S);
    rowsoftmax_kernel<<<NQ, 256, 0, stream>>>(S);
  } else {  // SAFE: norms only in ws
    float* qq = (float*)(ws);
    float* kk = (float*)(ws + 32768);
    prep_norms_kernel<<<4096, 256, 0, stream>>>(q, k, qq, kk);
    gemm_safe_kernel<<<dim3(64, 64), 256, 0, stream>>>(q, k, qq, kk, S);
    rowsoftmax_kernel<<<NQ, 256, 0, stream>>>(S);
  }
}

// Round 4
// 427.866 us; speedup vs baseline: 1.1500x; 1.0911x over previous
//
#include <hip/hip_runtime.h>
#include <stdint.h>

// Problem: Q[8192,512] f32, K[8192,512] f32 ->
//   scores_ij = -0.5*(sqrt(n2 + c*qd^2) + sqrt(n2 + c*kd^2)),  out = softmax
// Round-4 (on R3's measured counters: MfmaUtil 16.8, VALUBusy 62, 9.4M LDS
// bank conflicts, LDS 26KB):
//   - XOR-swizzled LDS tile layout (slot = g ^ ((row>>1)&3)) kills the 8-way
//     frag-read bank conflict (16 lanes -> 2/bank = free)
//   - __builtin_amdgcn_sqrtf: raw v_sqrt_f32 instead of libm guarded sequence
//   - epilogue transpose reuses the A/B LDS region: block LDS 26624 -> 16384

#define NQ 8192
#define NK 8192
#define DIM 512
#define CSCALE 0.01f

typedef float f32x4 __attribute__((ext_vector_type(4)));
typedef short s16x8 __attribute__((ext_vector_type(8)));
typedef unsigned short u16x4 __attribute__((ext_vector_type(4)));

__device__ __forceinline__ unsigned short f2bf(float x) {
  union { float f; uint32_t u; } c; c.f = x;
  uint32_t u = c.u;
  return (unsigned short)((u + 0x7fffu + ((u >> 16) & 1u)) >> 16);
}

__device__ __forceinline__ float bf2f(unsigned short h) {
  union { uint32_t u; float f; } c; c.u = ((uint32_t)h) << 16;
  return c.f;
}

__device__ __forceinline__ s16x8 pack8(f32x4 a, f32x4 b) {
  s16x8 r;
  r[0]=(short)f2bf(a.x); r[1]=(short)f2bf(a.y);
  r[2]=(short)f2bf(a.z); r[3]=(short)f2bf(a.w);
  r[4]=(short)f2bf(b.x); r[5]=(short)f2bf(b.y);
  r[6]=(short)f2bf(b.z); r[7]=(short)f2bf(b.w);
  return r;
}

#define GLOAD_LDS16(g, l)                                                      \
  __builtin_amdgcn_global_load_lds(                                            \
      (const __attribute__((address_space(1))) void*)(g),                      \
      (__attribute__((address_space(3))) void*)(l), 16, 0, 0)

// ------------------------------------------------------------- prep (FAST)
__global__ __launch_bounds__(256) void prep_full_kernel(
    const float* __restrict__ q, const float* __restrict__ k,
    unsigned short* __restrict__ qbf, unsigned short* __restrict__ kbf,
    float* __restrict__ qq, float* __restrict__ kk) {
  int rowg = blockIdx.x * 4 + (threadIdx.x >> 6);  // 0..16383
  int lane = threadIdx.x & 63;
  const float* src; unsigned short* dst; float* nrm; int row;
  if (rowg < NQ) { src = q; dst = qbf; nrm = qq; row = rowg; }
  else           { src = k; dst = kbf; nrm = kk; row = rowg - NQ; }
  const float* p = src + (size_t)row * DIM + lane * 8;
  f32x4 a = *(const f32x4*)p;
  f32x4 b = *(const f32x4*)(p + 4);
  float ss = a.x*a.x + a.y*a.y + a.z*a.z + a.w*a.w
           + b.x*b.x + b.y*b.y + b.z*b.z + b.w*b.w;
  *(s16x8*)(dst + (size_t)row * DIM + lane * 8) = pack8(a, b);
#pragma unroll
  for (int mask = 1; mask < 64; mask <<= 1) ss += __shfl_xor(ss, mask, 64);
  if (lane == 0) nrm[row] = ss;
}

// ------------------------------------------------------------- prep (SAFE)
__global__ __launch_bounds__(256) void prep_norms_kernel(
    const float* __restrict__ q, const float* __restrict__ k,
    float* __restrict__ qq, float* __restrict__ kk) {
  int rowg = blockIdx.x * 4 + (threadIdx.x >> 6);
  int lane = threadIdx.x & 63;
  const float* src; float* nrm; int row;
  if (rowg < NQ) { src = q; nrm = qq; row = rowg; }
  else           { src = k; nrm = kk; row = rowg - NQ; }
  const float* p = src + (size_t)row * DIM + lane * 8;
  f32x4 a = *(const f32x4*)p;
  f32x4 b = *(const f32x4*)(p + 4);
  float ss = a.x*a.x + a.y*a.y + a.z*a.z + a.w*a.w
           + b.x*b.x + b.y*b.y + b.z*b.z + b.w*b.w;
#pragma unroll
  for (int mask = 1; mask < 64; mask <<= 1) ss += __shfl_xor(ss, mask, 64);
  if (lane == 0) nrm[row] = ss;
}

// ---- score from qk accumulator --------------------------------------------
__device__ __forceinline__ float score_fn(float qkv, float qqv, float kkv) {
  float n2 = fmaxf(qqv + kkv - 2.f * qkv, 0.f);
  float qd = qqv - qkv;
  float kd = qkv - kkv;
  return -0.5f * (__builtin_amdgcn_sqrtf(n2 + CSCALE * qd * qd) +
                  __builtin_amdgcn_sqrtf(n2 + CSCALE * kd * kd));
}

// ------------------------------------------------------------- GEMM (FAST)
// 128x128 tile, 256 threads = 4 waves (2x2 of 64x64), BK=32, 16x16x32 MFMA.
// LDS: single 16 KB buffer. K-loop: A = smem[0:8K), B = smem[8K:16K), both
// XOR-swizzled: 16B k-group g of row r lives at slot g ^ ((r>>1)&3).
// Epilogue reuses smem[0:10K) as 4 wave-private 16x80 transpose pads.
__global__ __launch_bounds__(256) void gemm_exp_kernel(
    const unsigned short* __restrict__ qbf, const unsigned short* __restrict__ kbf,
    const float* __restrict__ qq, const float* __restrict__ kk,
    unsigned short* __restrict__ E) {
  __shared__ alignas(16) unsigned short smem[8192];  // 16 KB total
  const int tid = threadIdx.x;
  const int m0 = blockIdx.y * 128;
  const int n0 = blockIdx.x * 128;
  const int wave = tid >> 6, lane = tid & 63;
  const int wr = wave >> 1, wc = wave & 1;
  const int quad = lane >> 4, lcol = lane & 15;

  // staging: thread t covers row srow (and srow+64), 16B slot (t&3); the
  // global k-group fetched is XOR-permuted so LDS slot g holds group
  // g ^ ((row>>1)&3). (row+64 keeps the same key: +64>>1 = +32, &3 = 0.)
  const int srow = tid >> 2;                       // 0..63
  const int gsw = (tid & 3) ^ ((srow >> 1) & 3);   // global 16B group to fetch
  const unsigned short* ga = qbf + (size_t)(m0 + srow) * DIM + gsw * 8;
  const unsigned short* gb = kbf + (size_t)(n0 + srow) * DIM + gsw * 8;
  char* la0 = (char*)smem + wave * 1024;           // wave-uniform LDS base
  char* lb0 = (char*)smem + 8192 + wave * 1024;

  f32x4 acc[4][4];
#pragma unroll
  for (int mi = 0; mi < 4; ++mi)
#pragma unroll
    for (int ni = 0; ni < 4; ++ni) acc[mi][ni] = f32x4{0.f, 0.f, 0.f, 0.f};

  const s16x8* lA8 = (const s16x8*)smem;           // 16B-granular view
  const s16x8* lB8 = (const s16x8*)(smem + 4096);
  const int arow = wr * 64 + lcol;   // A frag: m = lane&15, k = quad*8+j
  const int brow = wc * 64 + lcol;
  const int swz = (lcol >> 1) & 3;   // = ((arow + mi*16)>>1)&3 for all mi
  const int qsw = quad ^ swz;        // swizzled slot of logical group `quad`

  for (int kt = 0; kt < DIM / 32; ++kt) {
    const int ko = kt * 32;
    GLOAD_LDS16(ga + ko, la0);
    GLOAD_LDS16(ga + ko + 64 * DIM, la0 + 4096);
    GLOAD_LDS16(gb + ko, lb0);
    GLOAD_LDS16(gb + ko + 64 * DIM, lb0 + 4096);
    __syncthreads();
    s16x8 af[4], bfr[4];
#pragma unroll
    for (int mi = 0; mi < 4; ++mi) af[mi] = lA8[(arow + mi * 16) * 4 + qsw];
#pragma unroll
    for (int ni = 0; ni < 4; ++ni) bfr[ni] = lB8[(brow + ni * 16) * 4 + qsw];
#pragma unroll
    for (int mi = 0; mi < 4; ++mi)
#pragma unroll
      for (int ni = 0; ni < 4; ++ni)
        acc[mi][ni] = __builtin_amdgcn_mfma_f32_16x16x32_bf16(
            af[mi], bfr[ni], acc[mi][ni], 0, 0, 0);
    __syncthreads();  // also drains all LDS ops -> smem reusable after loop
  }

  // ---- epilogue: E = exp(score) -> bf16, LDS transpose, 128B-line stores --
  // C/D layout: col = lane&15, row = quad*4 + reg  [verified R2/R3 pass]
  unsigned short* tw = smem + wave * 1280;  // wave-private 16x80 shorts
  float kkv[4];
#pragma unroll
  for (int ni = 0; ni < 4; ++ni) kkv[ni] = kk[n0 + wc * 64 + ni * 16 + lcol];
#pragma unroll
  for (int mi = 0; mi < 4; ++mi) {
    const int ibase = m0 + wr * 64 + mi * 16 + quad * 4;  // rows ibase..+3
    float qqv[4];
#pragma unroll
    for (int r = 0; r < 4; ++r) qqv[r] = qq[ibase + r];
    // write: row16 = quad*4+r, stored col-group = ni ^ quad (bank spread)
#pragma unroll
    for (int ni = 0; ni < 4; ++ni)
#pragma unroll
      for (int r = 0; r < 4; ++r) {
        float e = __expf(score_fn(acc[mi][ni][r], qqv[r], kkv[ni]));
        tw[(quad * 4 + r) * 80 + ((ni ^ quad) * 16 + lcol)] = f2bf(e);
      }
    // read 16B/lane, 8 lanes cover one row's 64 cols = 128B line
#pragma unroll
    for (int j = 0; j < 2; ++j) {
      const int row16 = (lane >> 3) + j * 8;
      const int g = (lane & 7) >> 1;            // global col group 0..3
      const int off = row16 * 80 + ((g ^ (row16 >> 2)) * 16) + (lane & 1) * 8;
      s16x8 vv = *(const s16x8*)(tw + off);
      const int rowg = m0 + wr * 64 + mi * 16 + row16;
      *(s16x8*)(E + (size_t)rowg * NK + n0 + wc * 64 + (lane & 7) * 8) = vv;
    }
  }
}

// ------------------------------------------------- row sum + scale (FAST)
__global__ __launch_bounds__(256) void rowsum_scale_kernel(
    const unsigned short* __restrict__ E, float* __restrict__ out) {
  __shared__ float red[4];
  const int t = threadIdx.x;
  const int wave = t >> 6, lane = t & 63;
  const unsigned short* Erow = E + (size_t)blockIdx.x * NK;
  float* Orow = out + (size_t)blockIdx.x * NK;
  u16x4 ev[8];
  float s = 0.f;
#pragma unroll
  for (int j = 0; j < 8; ++j) {
    ev[j] = *(const u16x4*)(Erow + j * 1024 + t * 4);
    s += (bf2f(ev[j][0]) + bf2f(ev[j][1])) + (bf2f(ev[j][2]) + bf2f(ev[j][3]));
  }
#pragma unroll
  for (int mask = 1; mask < 64; mask <<= 1) s += __shfl_xor(s, mask, 64);
  if (lane == 0) red[wave] = s;
  __syncthreads();
  float z = 1.0f / ((red[0] + red[1]) + (red[2] + red[3]));
#pragma unroll
  for (int j = 0; j < 8; ++j) {
    f32x4 v;
    v.x = bf2f(ev[j][0]) * z;
    v.y = bf2f(ev[j][1]) * z;
    v.z = bf2f(ev[j][2]) * z;
    v.w = bf2f(ev[j][3]) * z;
    *(f32x4*)(Orow + j * 1024 + t * 4) = v;
  }
}

// ================== round-2 verified fallback kernels (MID / SAFE) ==========
__device__ __forceinline__ void score_epilogue(
    const f32x4 acc[4][4], const float* __restrict__ qq,
    const float* __restrict__ kk, float* __restrict__ S,
    int m0, int n0, int wr, int wc, int quad, int lcol) {
  float kkv[4];
#pragma unroll
  for (int ni = 0; ni < 4; ++ni) kkv[ni] = kk[n0 + wc * 64 + ni * 16 + lcol];
#pragma unroll
  for (int mi = 0; mi < 4; ++mi) {
    const int ibase = m0 + wr * 64 + mi * 16 + quad * 4;
    float qqv[4];
#pragma unroll
    for (int r = 0; r < 4; ++r) qqv[r] = qq[ibase + r];
#pragma unroll
    for (int ni = 0; ni < 4; ++ni) {
      const int col = n0 + wc * 64 + ni * 16 + lcol;
#pragma unroll
      for (int r = 0; r < 4; ++r)
        S[(size_t)(ibase + r) * NK + col] = score_fn(acc[mi][ni][r], qqv[r], kkv[ni]);
    }
  }
}

__global__ __launch_bounds__(256) void gemm_fast_kernel(
    const unsigned short* __restrict__ qbf, const unsigned short* __restrict__ kbf,
    const float* __restrict__ qq, const float* __restrict__ kk,
    float* __restrict__ S) {
  __shared__ unsigned short lA[128 * 32];
  __shared__ unsigned short lB[128 * 32];
  const int tid = threadIdx.x;
  const int m0 = blockIdx.y * 128;
  const int n0 = blockIdx.x * 128;
  const int wave = tid >> 6, lane = tid & 63;
  const int wr = wave >> 1, wc = wave & 1;
  const int quad = lane >> 4, lcol = lane & 15;
  const unsigned short* ga = qbf + (size_t)(m0 + (tid >> 2)) * DIM + (tid & 3) * 8;
  const unsigned short* gb = kbf + (size_t)(n0 + (tid >> 2)) * DIM + (tid & 3) * 8;
  char* la0 = (char*)lA + wave * 1024;
  char* lb0 = (char*)lB + wave * 1024;
  f32x4 acc[4][4];
#pragma unroll
  for (int mi = 0; mi < 4; ++mi)
#pragma unroll
    for (int ni = 0; ni < 4; ++ni) acc[mi][ni] = f32x4{0.f, 0.f, 0.f, 0.f};
  const s16x8* lA8 = (const s16x8*)lA;
  const s16x8* lB8 = (const s16x8*)lB;
  const int arow = wr * 64 + lcol;
  const int brow = wc * 64 + lcol;
  for (int kt = 0; kt < DIM / 32; ++kt) {
    const int ko = kt * 32;
    GLOAD_LDS16(ga + ko, la0);
    GLOAD_LDS16(ga + ko + 64 * DIM, la0 + 4096);
    GLOAD_LDS16(gb + ko, lb0);
    GLOAD_LDS16(gb + ko + 64 * DIM, lb0 + 4096);
    __syncthreads();
    s16x8 af[4], bfr[4];
#pragma unroll
    for (int mi = 0; mi < 4; ++mi) af[mi] = lA8[(arow + mi * 16) * 4 + quad];
#pragma unroll
    for (int ni = 0; ni < 4; ++ni) bfr[ni] = lB8[(brow + ni * 16) * 4 + quad];
#pragma unroll
    for (int mi = 0; mi < 4; ++mi)
#pragma unroll
      for (int ni = 0; ni < 4; ++ni)
        acc[mi][ni] = __builtin_amdgcn_mfma_f32_16x16x32_bf16(
            af[mi], bfr[ni], acc[mi][ni], 0, 0, 0);
    __syncthreads();
  }
  score_epilogue(acc, qq, kk, S, m0, n0, wr, wc, quad, lcol);
}

__global__ __launch_bounds__(256) void gemm_safe_kernel(
    const float* __restrict__ q, const float* __restrict__ k,
    const float* __restrict__ qq, const float* __restrict__ kk,
    float* __restrict__ S) {
  __shared__ unsigned short lA[128 * 32];
  __shared__ unsigned short lB[128 * 32];
  const int tid = threadIdx.x;
  const int m0 = blockIdx.y * 128;
  const int n0 = blockIdx.x * 128;
  const int wave = tid >> 6, lane = tid & 63;
  const int wr = wave >> 1, wc = wave & 1;
  const int quad = lane >> 4, lcol = lane & 15;
  const float* gaf = q + (size_t)(m0 + (tid >> 1)) * DIM + (tid & 1) * 16;
  const float* gbf = k + (size_t)(n0 + (tid >> 1)) * DIM + (tid & 1) * 16;
  unsigned short* wA = lA + (tid >> 1) * 32 + (tid & 1) * 16;
  unsigned short* wB = lB + (tid >> 1) * 32 + (tid & 1) * 16;
  f32x4 acc[4][4];
#pragma unroll
  for (int mi = 0; mi < 4; ++mi)
#pragma unroll
    for (int ni = 0; ni < 4; ++ni) acc[mi][ni] = f32x4{0.f, 0.f, 0.f, 0.f};
  const s16x8* lA8 = (const s16x8*)lA;
  const s16x8* lB8 = (const s16x8*)lB;
  const int arow = wr * 64 + lcol;
  const int brow = wc * 64 + lcol;
  for (int kt = 0; kt < DIM / 32; ++kt) {
    const float* pa = gaf + kt * 32;
    const float* pb = gbf + kt * 32;
    f32x4 a0 = *(const f32x4*)(pa), a1 = *(const f32x4*)(pa + 4);
    f32x4 a2 = *(const f32x4*)(pa + 8), a3 = *(const f32x4*)(pa + 12);
    f32x4 b0 = *(const f32x4*)(pb), b1 = *(const f32x4*)(pb + 4);
    f32x4 b2 = *(const f32x4*)(pb + 8), b3 = *(const f32x4*)(pb + 12);
    *(s16x8*)wA = pack8(a0, a1);
    *(s16x8*)(wA + 8) = pack8(a2, a3);
    *(s16x8*)wB = pack8(b0, b1);
    *(s16x8*)(wB + 8) = pack8(b2, b3);
    __syncthreads();
    s16x8 af[4], bfr[4];
#pragma unroll
    for (int mi = 0; mi < 4; ++mi) af[mi] = lA8[(arow + mi * 16) * 4 + quad];
#pragma unroll
    for (int ni = 0; ni < 4; ++ni) bfr[ni] = lB8[(brow + ni * 16) * 4 + quad];
#pragma unroll
    for (int mi = 0; mi < 4; ++mi)
#pragma unroll
      for (int ni = 0; ni < 4; ++ni)
        acc[mi][ni] = __builtin_amdgcn_mfma_f32_16x16x32_bf16(
            af[mi], bfr[ni], acc[mi][ni], 0, 0, 0);
    __syncthreads();
  }
  score_epilogue(acc, qq, kk, S, m0, n0, wr, wc, quad, lcol);
}

__global__ __launch_bounds__(256) void rowsoftmax_kernel(float* __restrict__ S) {
  __shared__ float red[8];
  const int t = threadIdx.x;
  const int wave = t >> 6, lane = t & 63;
  float* Srow = S + (size_t)blockIdx.x * NK;
  f32x4 v[8];
  float m = -1e30f;
#pragma unroll
  for (int j = 0; j < 8; ++j) {
    v[j] = *(const f32x4*)(Srow + j * 1024 + t * 4);
    m = fmaxf(m, fmaxf(fmaxf(v[j].x, v[j].y), fmaxf(v[j].z, v[j].w)));
  }
#pragma unroll
  for (int mask = 1; mask < 64; mask <<= 1) m = fmaxf(m, __shfl_xor(m, mask, 64));
  if (lane == 0) red[wave] = m;
  __syncthreads();
  m = fmaxf(fmaxf(red[0], red[1]), fmaxf(red[2], red[3]));
  float s = 0.f;
#pragma unroll
  for (int j = 0; j < 8; ++j) {
    v[j].x = __expf(v[j].x - m);
    v[j].y = __expf(v[j].y - m);
    v[j].z = __expf(v[j].z - m);
    v[j].w = __expf(v[j].w - m);
    s += (v[j].x + v[j].y) + (v[j].z + v[j].w);
  }
#pragma unroll
  for (int mask = 1; mask < 64; mask <<= 1) s += __shfl_xor(s, mask, 64);
  if (lane == 0) red[4 + wave] = s;
  __syncthreads();
  float z = 1.0f / ((red[4] + red[5]) + (red[6] + red[7]));
#pragma unroll
  for (int j = 0; j < 8; ++j) {
    v[j].x *= z; v[j].y *= z; v[j].z *= z; v[j].w *= z;
    *(f32x4*)(Srow + j * 1024 + t * 4) = v[j];
  }
}

// ---------------------------------------------------------------- launch
extern "C" void kernel_launch(void* const* d_in, const int* in_sizes, int n_in,
                              void* d_out, int out_size, void* d_ws, size_t ws_size,
                              hipStream_t stream) {
  const float* q = (const float*)d_in[0];
  const float* k = (const float*)d_in[1];
  float* S = (float*)d_out;
  char* ws = (char*)d_ws;

  // FAST: qbf(8M) + kbf(8M) + qq(32K) + kk(32K) + E(128M) = 151,126,016 B
  if (ws_size >= (size_t)151126016) {
    unsigned short* qbf = (unsigned short*)(ws);
    unsigned short* kbf = (unsigned short*)(ws + 8388608);
    float* qq = (float*)(ws + 16777216);
    float* kk = (float*)(ws + 16777216 + 32768);
    unsigned short* E = (unsigned short*)(ws + 16908288);
    prep_full_kernel<<<4096, 256, 0, stream>>>(q, k, qbf, kbf, qq, kk);
    gemm_exp_kernel<<<dim3(64, 64), 256, 0, stream>>>(qbf, kbf, qq, kk, E);
    rowsum_scale_kernel<<<NQ, 256, 0, stream>>>(E, S);
  } else if (ws_size >= (size_t)16842752) {  // MID: round-2 verified path
    unsigned short* qbf = (unsigned short*)(ws);
    unsigned short* kbf = (unsigned short*)(ws + 8388608);
    float* qq = (float*)(ws + 16777216);
    float* kk = (float*)(ws + 16777216 + 32768);
    prep_full_kernel<<<4096, 256, 0, stream>>>(q, k, qbf, kbf, qq, kk);
    gemm_fast_kernel<<<dim3(64, 64), 256, 0, stream>>>(qbf, kbf, qq, kk, S);
    rowsoftmax_kernel<<<NQ, 256, 0, stream>>>(S);
  } else {  // SAFE: norms only in ws
    float* qq = (float*)(ws);
    float* kk = (float*)(ws + 32768);
    prep_norms_kernel<<<4096, 256, 0, stream>>>(q, k, qq, kk);
    gemm_safe_kernel<<<dim3(64, 64), 256, 0, stream>>>(q, k, qq, kk, S);
    rowsoftmax_kernel<<<NQ, 256, 0, stream>>>(S);
  }
}